// Round 2
// baseline (508.165 us; speedup 1.0000x reference)
//
#include <hip/hip_runtime.h>
#include <hip/hip_bf16.h>

#define DIMC 192
#define NHEAD 6
#define LTOT 3136
#define HQKV 576
#define MTOT 100352

using bf16x8 = __attribute__((ext_vector_type(8))) short;
using f32x4  = __attribute__((ext_vector_type(4))) float;

static __device__ __forceinline__ unsigned short f2bf(float f) {
  unsigned u = __builtin_bit_cast(unsigned, f);
  u = (u + 0x7FFFu + ((u >> 16) & 1u)) >> 16;
  return (unsigned short)u;
}
static __device__ __forceinline__ float bf2f(unsigned short u) {
  unsigned v = ((unsigned)u) << 16;
  return __builtin_bit_cast(float, v);
}
static __device__ __forceinline__ int iabs(int a) { return a < 0 ? -a : a; }

// ---- prep: weights -> bf16 W^T [N][K]; conv w -> [9][192]; BN fold ----
__global__ __launch_bounds__(256) void prep_k(
    const float* __restrict__ qkv_w, const float* __restrict__ proj_w,
    const float* __restrict__ fc1_w, const float* __restrict__ fc2_w,
    const float* __restrict__ conv_w,
    const float* __restrict__ bn_g, const float* __restrict__ bn_b,
    const float* __restrict__ bn_m, const float* __restrict__ bn_v,
    unsigned short* __restrict__ qkvT, unsigned short* __restrict__ projT,
    unsigned short* __restrict__ fc1T, unsigned short* __restrict__ fc2T,
    float* __restrict__ convT, float* __restrict__ bnsc, float* __restrict__ bnsh)
{
  int idx = blockIdx.x * 256 + threadIdx.x;
  if (idx < 110592) { int n = idx / 192, k = idx % 192; qkvT[idx] = f2bf(qkv_w[k * 576 + n]); return; }
  idx -= 110592;
  if (idx < 36864)  { int n = idx / 192, k = idx % 192; projT[idx] = f2bf(proj_w[k * 192 + n]); return; }
  idx -= 36864;
  if (idx < 147456) { int n = idx / 192, k = idx % 192; fc1T[idx] = f2bf(fc1_w[k * 768 + n]); return; }
  idx -= 147456;
  if (idx < 147456) { int n = idx / 768, k = idx % 768; fc2T[idx] = f2bf(fc2_w[k * 192 + n]); return; }
  idx -= 147456;
  if (idx < 1728)   { int tap = idx / 192, c = idx % 192; convT[idx] = conv_w[c * 9 + tap]; return; }
  idx -= 1728;
  if (idx < 192) {
    float s = bn_g[idx] * rsqrtf(bn_v[idx] + 1e-5f);
    bnsc[idx] = s; bnsh[idx] = bn_b[idx] - bn_m[idx] * s;
  }
}

// ---- LN1 + window partition: x (B,L,D) f32 -> h1 (windowed M,D) bf16 ----
__global__ __launch_bounds__(256) void ln1_k(
    const float* __restrict__ x, const float* __restrict__ g,
    const float* __restrict__ b, unsigned short* __restrict__ h1)
{
  const int grp = threadIdx.x >> 6, l = threadIdx.x & 63;
  const int m = blockIdx.x * 4 + grp;
  const int w = m / 49, t = m % 49;
  const int bb = w >> 6, win = w & 63;
  const int lpix = ((win >> 3) * 7 + t / 7) * 56 + (win & 7) * 7 + t % 7;
  const float* row = x + ((size_t)bb * LTOT + lpix) * DIMC;
  const bool act = l < 48;
  const int c = l * 4;
  float4 v = make_float4(0.f, 0.f, 0.f, 0.f);
  if (act) v = *(const float4*)(row + c);
  float s = v.x + v.y + v.z + v.w;
  float ss = v.x * v.x + v.y * v.y + v.z * v.z + v.w * v.w;
  #pragma unroll
  for (int off = 1; off < 64; off <<= 1) { s += __shfl_xor(s, off); ss += __shfl_xor(ss, off); }
  float mean = s * (1.f / 192.f);
  float rstd = rsqrtf(ss * (1.f / 192.f) - mean * mean + 1e-5f);
  if (act) {
    float4 gg = *(const float4*)(g + c);
    float4 bv = *(const float4*)(b + c);
    ushort4 o;
    o.x = f2bf((v.x - mean) * rstd * gg.x + bv.x);
    o.y = f2bf((v.y - mean) * rstd * gg.y + bv.y);
    o.z = f2bf((v.z - mean) * rstd * gg.z + bv.z);
    o.w = f2bf((v.w - mean) * rstd * gg.w + bv.w);
    *(ushort4*)(h1 + (size_t)m * DIMC + c) = o;
  }
}

// ---- generic bf16 MFMA GEMM, 64x64 tile, K staged in 192-chunks ----
// EPI 0: out bf16 = acc+bias                          (qkv)
// EPI 1: out f32 (win-scatter) = res(f32) + acc+bias  (proj + residual -> d_out)
// EPI 2: out bf16 = gelu(acc+bias)                    (fc1 half)
// EPI 3: out f32 = res(f32) + acc       (no bias)     (fc2 pass1 accumulate)
// EPI 4: out f32 = res(bf16) + acc+bias               (fc2 pass0, res = x2 bf16)
template<int EPI>
__global__ __launch_bounds__(256) void gemm_k(
    const unsigned short* __restrict__ Ag, const unsigned short* __restrict__ Bt,
    const float* __restrict__ bias, void* __restrict__ outp,
    const void* __restrict__ res, int M, int N, int K, int ldb)
{
  __shared__ unsigned short As[64 * 200];
  __shared__ unsigned short Bs[64 * 200];
  const int tid = threadIdx.x;
  const int l = tid & 63, wv = tid >> 6;
  const int u = l >> 4, ll = l & 15;
  const int wm = wv >> 1, wn = wv & 1;
  const int m0 = blockIdx.x * 64, n0 = blockIdx.y * 64;
  const f32x4 fz = {0.f, 0.f, 0.f, 0.f};

  f32x4 acc[2][2];
  acc[0][0] = fz; acc[0][1] = fz; acc[1][0] = fz; acc[1][1] = fz;

  const int nch = K / 192;
  for (int kc = 0; kc < nch; ++kc) {
    const int k0 = kc * 192;
    #pragma unroll
    for (int it = 0; it < 6; ++it) {
      int idx = tid + it * 256;
      int row = idx / 24, kk = idx % 24;
      *(int4*)&Bs[row * 200 + kk * 8] = *(const int4*)&Bt[(size_t)(n0 + row) * ldb + k0 + kk * 8];
      *(int4*)&As[row * 200 + kk * 8] = *(const int4*)&Ag[(size_t)(m0 + row) * K + k0 + kk * 8];
    }
    __syncthreads();
    #pragma unroll
    for (int kk = 0; kk < 6; ++kk) {
      bf16x8 af[2], bfr[2];
      #pragma unroll
      for (int mt = 0; mt < 2; ++mt)
        af[mt] = *(const bf16x8*)&As[(wm * 32 + mt * 16 + ll) * 200 + kk * 32 + u * 8];
      #pragma unroll
      for (int nt = 0; nt < 2; ++nt)
        bfr[nt] = *(const bf16x8*)&Bs[(wn * 32 + nt * 16 + ll) * 200 + kk * 32 + u * 8];
      #pragma unroll
      for (int mt = 0; mt < 2; ++mt)
        #pragma unroll
        for (int nt = 0; nt < 2; ++nt)
          acc[mt][nt] = __builtin_amdgcn_mfma_f32_16x16x32_bf16(af[mt], bfr[nt], acc[mt][nt], 0, 0, 0);
    }
    __syncthreads();
  }

  #pragma unroll
  for (int mt = 0; mt < 2; ++mt)
  #pragma unroll
  for (int r = 0; r < 4; ++r) {
    int m = m0 + wm * 32 + mt * 16 + u * 4 + r;
    size_t rowbase = 0;
    if (EPI == 1) {
      int w = m / 49, t = m % 49;
      int bb = w >> 6, win = w & 63;
      int lpix = ((win >> 3) * 7 + t / 7) * 56 + (win & 7) * 7 + t % 7;
      rowbase = ((size_t)bb * LTOT + lpix) * DIMC;
    }
    #pragma unroll
    for (int nt = 0; nt < 2; ++nt) {
      int n = n0 + wn * 32 + nt * 16 + ll;
      float v = acc[mt][nt][r];
      if (EPI != 3) v += bias[n];
      if (EPI == 0) {
        ((unsigned short*)outp)[(size_t)m * N + n] = f2bf(v);
      } else if (EPI == 1) {
        ((float*)outp)[rowbase + n] = ((const float*)res)[rowbase + n] + v;
      } else if (EPI == 2) {
        float gl = 0.5f * v * (1.f + erff(v * 0.70710678118654752f));
        ((unsigned short*)outp)[(size_t)m * N + n] = f2bf(gl);
      } else if (EPI == 3) {
        size_t o = (size_t)m * N + n;
        ((float*)outp)[o] = ((const float*)res)[o] + v;
      } else {
        size_t o = (size_t)m * N + n;
        ((float*)outp)[o] = bf2f(((const unsigned short*)res)[o]) + v;
      }
    }
  }
}

// ---- windowed attention: one block per window, loops 6 heads ----
__global__ __launch_bounds__(256) void attn_k(
    const unsigned short* __restrict__ qkv, const float* __restrict__ attn_bias,
    unsigned short* __restrict__ o)
{
  __shared__ unsigned short Qs[64 * 40];
  __shared__ unsigned short Ks[64 * 40];
  __shared__ unsigned short Vt[32 * 72];
  __shared__ unsigned short Ps[64 * 72];
  __shared__ float S[64 * 65];
  __shared__ float bias_s[52];
  const int tid = threadIdx.x;
  const int l = tid & 63, wv = tid >> 6;
  const int u = l >> 4, ll = l & 15;
  const int w = blockIdx.x;
  const f32x4 fz = {0.f, 0.f, 0.f, 0.f};

  for (int i = tid; i < 15 * 40; i += 256) {
    Qs[(49 + i / 40) * 40 + i % 40] = 0;
    Ks[(49 + i / 40) * 40 + i % 40] = 0;
  }
  for (int i = tid; i < 32 * 15; i += 256) Vt[(i / 15) * 72 + 49 + i % 15] = 0;

  for (int h = 0; h < NHEAD; ++h) {
    __syncthreads();  // protects Qs/Ks/Vt/bias_s reuse across heads
    if (tid < 49) bias_s[tid] = attn_bias[h * 49 + tid];
    #pragma unroll
    for (int it = 0; it < 3; ++it) {
      int idx = tid + it * 256;
      if (idx < 588) {
        int row = idx / 12, g = idx % 12;
        int4 v = *(const int4*)&qkv[((size_t)w * 49 + row) * HQKV + h * 96 + g * 8];
        if (g < 4) *(int4*)&Qs[row * 40 + g * 8] = v;
        else if (g < 8) *(int4*)&Ks[row * 40 + (g - 4) * 8] = v;
        else {
          union { int4 v4; unsigned short us[8]; } uu; uu.v4 = v;
          int d0 = (g - 8) * 8;
          #pragma unroll
          for (int e = 0; e < 8; ++e) Vt[(d0 + e) * 72 + row] = uu.us[e];
        }
      }
    }
    __syncthreads();
    bf16x8 qf = *(const bf16x8*)&Qs[(wv * 16 + ll) * 40 + u * 8];
    f32x4 sc[4];
    #pragma unroll
    for (int nj = 0; nj < 4; ++nj) {
      bf16x8 kf = *(const bf16x8*)&Ks[(nj * 16 + ll) * 40 + u * 8];
      sc[nj] = __builtin_amdgcn_mfma_f32_16x16x32_bf16(qf, kf, fz, 0, 0, 0);
    }
    #pragma unroll
    for (int nj = 0; nj < 4; ++nj)
    #pragma unroll
    for (int r = 0; r < 4; ++r) {
      int i = wv * 16 + u * 4 + r;
      int j = nj * 16 + ll;
      float val = -1e30f;
      if (i < 49 && j < 49) {
        int bi = iabs(i / 7 - j / 7) * 7 + iabs(i % 7 - j % 7);
        val = sc[nj][r] * 0.17677669529663689f + bias_s[bi];
      }
      S[i * 65 + j] = val;
    }
    __syncthreads();
    {
      int row = tid >> 2, t4 = tid & 3;
      float mx = -1e30f;
      #pragma unroll
      for (int jj = 0; jj < 16; ++jj) mx = fmaxf(mx, S[row * 65 + t4 + jj * 4]);
      mx = fmaxf(mx, __shfl_xor(mx, 1));
      mx = fmaxf(mx, __shfl_xor(mx, 2));
      float pv[16], sum = 0.f;
      #pragma unroll
      for (int jj = 0; jj < 16; ++jj) {
        float p = __expf(S[row * 65 + t4 + jj * 4] - mx);
        pv[jj] = p; sum += p;
      }
      sum += __shfl_xor(sum, 1);
      sum += __shfl_xor(sum, 2);
      float inv = 1.f / sum;
      #pragma unroll
      for (int jj = 0; jj < 16; ++jj) Ps[row * 72 + t4 + jj * 4] = f2bf(pv[jj] * inv);
    }
    __syncthreads();
    f32x4 oacc[2]; oacc[0] = fz; oacc[1] = fz;
    #pragma unroll
    for (int kk = 0; kk < 2; ++kk) {
      bf16x8 pf = *(const bf16x8*)&Ps[(wv * 16 + ll) * 72 + kk * 32 + u * 8];
      #pragma unroll
      for (int nt = 0; nt < 2; ++nt) {
        bf16x8 vf = *(const bf16x8*)&Vt[(nt * 16 + ll) * 72 + kk * 32 + u * 8];
        oacc[nt] = __builtin_amdgcn_mfma_f32_16x16x32_bf16(pf, vf, oacc[nt], 0, 0, 0);
      }
    }
    #pragma unroll
    for (int nt = 0; nt < 2; ++nt)
    #pragma unroll
    for (int r = 0; r < 4; ++r) {
      int i = wv * 16 + u * 4 + r;
      if (i < 49) {
        int d = nt * 16 + ll;
        o[((size_t)w * 49 + i) * DIMC + h * 32 + d] = f2bf(oacc[nt][r]);
      }
    }
  }
}

// ---- depthwise 3x3 conv + BN + LN2: x1(d_out f32) -> x2 (bf16), h2 (bf16) ----
__global__ __launch_bounds__(256) void conv_k(
    const float* __restrict__ x1, const float* __restrict__ wT,
    const float* __restrict__ bnsc, const float* __restrict__ bnsh,
    const float* __restrict__ g2, const float* __restrict__ b2,
    unsigned short* __restrict__ x2, unsigned short* __restrict__ h2)
{
  const int grp = threadIdx.x >> 6, l = threadIdx.x & 63;
  const int gid = blockIdx.x * 4 + grp;
  const int b = gid / LTOT, p = gid % LTOT;
  const int i = p / 56, j = p % 56;
  const bool act = l < 48;
  const int c = l * 4;
  float4 acc = make_float4(0.f, 0.f, 0.f, 0.f);
  if (act) {
    #pragma unroll
    for (int di = -1; di <= 1; ++di)
    #pragma unroll
    for (int dj = -1; dj <= 1; ++dj) {
      int ni = i + di, nj = j + dj;
      if (ni >= 0 && ni < 56 && nj >= 0 && nj < 56) {
        float4 v = *(const float4*)&x1[((size_t)b * LTOT + ni * 56 + nj) * DIMC + c];
        float4 wv = *(const float4*)&wT[((di + 1) * 3 + (dj + 1)) * DIMC + c];
        acc.x += v.x * wv.x; acc.y += v.y * wv.y;
        acc.z += v.z * wv.z; acc.w += v.w * wv.w;
      }
    }
    float4 s4 = *(const float4*)&bnsc[c];
    float4 h4 = *(const float4*)&bnsh[c];
    acc.x = acc.x * s4.x + h4.x; acc.y = acc.y * s4.y + h4.y;
    acc.z = acc.z * s4.z + h4.z; acc.w = acc.w * s4.w + h4.w;
    ushort4 xv;
    xv.x = f2bf(acc.x); xv.y = f2bf(acc.y); xv.z = f2bf(acc.z); xv.w = f2bf(acc.w);
    *(ushort4*)&x2[(size_t)gid * DIMC + c] = xv;
  }
  float s = act ? acc.x + acc.y + acc.z + acc.w : 0.f;
  float ss = act ? acc.x * acc.x + acc.y * acc.y + acc.z * acc.z + acc.w * acc.w : 0.f;
  #pragma unroll
  for (int off = 1; off < 64; off <<= 1) { s += __shfl_xor(s, off); ss += __shfl_xor(ss, off); }
  float mean = s * (1.f / 192.f);
  float rstd = rsqrtf(ss * (1.f / 192.f) - mean * mean + 1e-5f);
  if (act) {
    float4 gg = *(const float4*)&g2[c];
    float4 bb = *(const float4*)&b2[c];
    ushort4 ov;
    ov.x = f2bf((acc.x - mean) * rstd * gg.x + bb.x);
    ov.y = f2bf((acc.y - mean) * rstd * gg.y + bb.y);
    ov.z = f2bf((acc.z - mean) * rstd * gg.z + bb.z);
    ov.w = f2bf((acc.w - mean) * rstd * gg.w + bb.w);
    *(ushort4*)&h2[(size_t)gid * DIMC + c] = ov;
  }
}

extern "C" void kernel_launch(void* const* d_in, const int* in_sizes, int n_in,
                              void* d_out, int out_size, void* d_ws, size_t ws_size,
                              hipStream_t stream) {
  const float* x      = (const float*)d_in[0];
  const float* ln1_g  = (const float*)d_in[1];
  const float* ln1_b  = (const float*)d_in[2];
  const float* qkv_w  = (const float*)d_in[3];
  const float* qkv_b  = (const float*)d_in[4];
  const float* proj_w = (const float*)d_in[5];
  const float* proj_b = (const float*)d_in[6];
  const float* attn_b = (const float*)d_in[7];
  const float* conv_w = (const float*)d_in[8];
  const float* bn_g   = (const float*)d_in[9];
  const float* bn_b   = (const float*)d_in[10];
  const float* bn_m   = (const float*)d_in[11];
  const float* bn_v   = (const float*)d_in[12];
  const float* ln2_g  = (const float*)d_in[13];
  const float* ln2_b  = (const float*)d_in[14];
  const float* fc1_w  = (const float*)d_in[15];
  const float* fc1_b  = (const float*)d_in[16];
  const float* fc2_w  = (const float*)d_in[17];
  const float* fc2_b  = (const float*)d_in[18];
  float* out = (float*)d_out;

  // workspace layout (bytes), peak 155,189,248 (~148 MiB):
  //   [0 .. 1 MiB)                 converted weights
  //   A [1MiB .. 1MiB+115.6MB):    qkv(bf16, steps 3-4) -> h2(bf16)@A, h3(bf16 M*384)@A+38.5MB
  //   B [A_end .. A_end+38.5MB):   h1(bf16) -> owin(bf16) -> x2(bf16)
  //   x1 (f32, attn-residual) lives in d_out (natural order), fully rewritten later.
  const size_t WREG = 0, AOFF = 1048576, BOFF = AOFF + 115605504;
  const size_t NEEDED = BOFF + 38535168;
  if (ws_size < NEEDED) return;  // diagnostic: clean mismatch instead of GPU fault

  char* ws = (char*)d_ws;
  unsigned short* qkvT  = (unsigned short*)(ws + WREG);
  unsigned short* projT = (unsigned short*)(ws + WREG + 221184);
  unsigned short* fc1T  = (unsigned short*)(ws + WREG + 294912);
  unsigned short* fc2T  = (unsigned short*)(ws + WREG + 589824);
  float*          convT = (float*)(ws + WREG + 884736);
  float*          bnsc  = (float*)(ws + WREG + 891648);
  float*          bnsh  = (float*)(ws + WREG + 892416);

  unsigned short* qkv  = (unsigned short*)(ws + AOFF);
  unsigned short* h2   = (unsigned short*)(ws + AOFF);
  unsigned short* h3   = (unsigned short*)(ws + AOFF + 38535168);
  unsigned short* h1   = (unsigned short*)(ws + BOFF);
  unsigned short* owin = (unsigned short*)(ws + BOFF);
  unsigned short* x2   = (unsigned short*)(ws + BOFF);
  float*          x1   = out;  // d_out doubles as the f32 attn-residual buffer

  prep_k<<<1736, 256, 0, stream>>>(qkv_w, proj_w, fc1_w, fc2_w, conv_w,
                                   bn_g, bn_b, bn_m, bn_v,
                                   qkvT, projT, fc1T, fc2T, convT, bnsc, bnsh);
  ln1_k<<<25088, 256, 0, stream>>>(x, ln1_g, ln1_b, h1);
  gemm_k<0><<<dim3(1568, 9), 256, 0, stream>>>(h1, qkvT, qkv_b, qkv, nullptr, MTOT, HQKV, 192, 192);
  attn_k<<<2048, 256, 0, stream>>>(qkv, attn_b, owin);
  gemm_k<1><<<dim3(1568, 3), 256, 0, stream>>>(owin, projT, proj_b, x1, x, MTOT, DIMC, 192, 192);
  conv_k<<<25088, 256, 0, stream>>>(x1, convT, bnsc, bnsh, ln2_g, ln2_b, x2, h2);
  // MLP, hidden split 2x384 to halve h3 footprint
  gemm_k<2><<<dim3(1568, 6), 256, 0, stream>>>(h2, fc1T, fc1_b, h3, nullptr, MTOT, 384, 192, 192);
  gemm_k<4><<<dim3(1568, 3), 256, 0, stream>>>(h3, fc2T, fc2_b, out, x2, MTOT, DIMC, 384, 768);
  gemm_k<2><<<dim3(1568, 6), 256, 0, stream>>>(h2, fc1T + 384 * 192, fc1_b + 384, h3, nullptr, MTOT, 384, 192, 192);
  gemm_k<3><<<dim3(1568, 3), 256, 0, stream>>>(h3, fc2T + 384, nullptr, out, out, MTOT, DIMC, 384, 768);
}